// Round 3
// baseline (95.323 us; speedup 1.0000x reference)
//
#include <hip/hip_runtime.h>
#include <hip/hip_bf16.h>

// ---------------------------------------------------------------------------
// MoE: router (argmax over 8 experts) + capacity drop + per-expert linear.
// Round 3:
//  - prep kernel fuses: router (float4-vectorized, one wave/token) + bf16
//    conversion of x (Xb, token order) + per-256-token histogram + We->bf16.
//  - expert GEMM: 128x128 BK=32 mfma_f32_16x16x32_bf16 with T3-minimum
//    2-phase pipeline (dbuf LDS, stage(next) BEFORE compute(cur), single
//    barrier per K-tile). A operand staged via per-lane GATHERED
//    global_load_lds straight from Xb (no compacted copy).
//  - dropped rows copied directly; kept rows written by GEMM scatter.
// ---------------------------------------------------------------------------

typedef short short8_t __attribute__((ext_vector_type(8)));
typedef float f32x4_t  __attribute__((ext_vector_type(4)));

typedef const unsigned int __attribute__((address_space(1))) gu32;
typedef unsigned int       __attribute__((address_space(3))) lu32;

__device__ __forceinline__ void async_load16(const void* gptr, void* lptr) {
    __builtin_amdgcn_global_load_lds((gu32*)gptr, (lu32*)lptr, 16, 0, 0);
}

// ---------------- fused prep: router + Xb + hist + We conversion -----------
__global__ void prep_kernel(const float* __restrict__ x,
                            const float* __restrict__ Wr,
                            const float* __restrict__ br,
                            const float* __restrict__ We,
                            int* __restrict__ ids,
                            int* __restrict__ blockHist,
                            __hip_bfloat16* __restrict__ Xb,
                            __hip_bfloat16* __restrict__ We16,
                            int N, int D, int nRouterBlocks, size_t weN) {
    if ((int)blockIdx.x < nRouterBlocks) {
        // ---- router part: one wave per token, float4 loads ----
        int token = blockIdx.x * 4 + (threadIdx.x >> 6);
        int lane  = threadIdx.x & 63;
        if (token >= N) return;
        const float4* xr = reinterpret_cast<const float4*>(x + (size_t)token * D);
        float acc[8];
#pragma unroll
        for (int e = 0; e < 8; ++e) acc[e] = 0.f;
#pragma unroll
        for (int p = 0; p < 4; ++p) {               // 4*64 float4 = 1024 floats
            float4 v = xr[p * 64 + lane];
            // write bf16 copy of x (token order)
            union { __hip_bfloat16 h[4]; uint2 u; } t;
            t.h[0] = __float2bfloat16(v.x); t.h[1] = __float2bfloat16(v.y);
            t.h[2] = __float2bfloat16(v.z); t.h[3] = __float2bfloat16(v.w);
            *reinterpret_cast<uint2*>(Xb + (size_t)token * D + (p * 64 + lane) * 4) = t.u;
#pragma unroll
            for (int e = 0; e < 8; ++e) {
                float4 w = reinterpret_cast<const float4*>(Wr + e * D)[p * 64 + lane];
                acc[e] += v.x * w.x + v.y * w.y + v.z * w.z + v.w * w.w;
            }
        }
#pragma unroll
        for (int e = 0; e < 8; ++e) {
            float s = acc[e];
            for (int off = 32; off > 0; off >>= 1)
                s += __shfl_xor(s, off, 64);
            acc[e] = s;
        }
        if (lane == 0) {
            int best = 0;
            float bv = acc[0] + br[0];
#pragma unroll
            for (int e = 1; e < 8; ++e) {
                float lv = acc[e] + br[e];
                if (lv > bv) { bv = lv; best = e; }  // strict >: first-max argmax
            }
            ids[token] = best;
            atomicAdd(&blockHist[(token >> 8) * 8 + best], 1);
        }
    } else {
        // ---- We fp32 -> bf16, grid-stride ----
        size_t b = blockIdx.x - nRouterBlocks;
        size_t nConvBlocks = gridDim.x - nRouterBlocks;
        size_t i = (b * blockDim.x + threadIdx.x) * 8;
        size_t stride = nConvBlocks * blockDim.x * 8;
        for (; i < weN; i += stride) {
            float4 v0 = *reinterpret_cast<const float4*>(We + i);
            float4 v1 = *reinterpret_cast<const float4*>(We + i + 4);
            union { __hip_bfloat16 h[8]; uint4 u; } t;
            t.h[0] = __float2bfloat16(v0.x); t.h[1] = __float2bfloat16(v0.y);
            t.h[2] = __float2bfloat16(v0.z); t.h[3] = __float2bfloat16(v0.w);
            t.h[4] = __float2bfloat16(v1.x); t.h[5] = __float2bfloat16(v1.y);
            t.h[6] = __float2bfloat16(v1.z); t.h[7] = __float2bfloat16(v1.w);
            *reinterpret_cast<uint4*>(We16 + i) = t.u;
        }
    }
}

// ---------------- fallback router (fp32 path) ----------------
__global__ void router_kernel(const float* __restrict__ x,
                              const float* __restrict__ Wr,
                              const float* __restrict__ br,
                              int* __restrict__ ids,
                              int N, int D) {
    int gtid = blockIdx.x * blockDim.x + threadIdx.x;
    int token = gtid >> 6;
    int lane  = threadIdx.x & 63;
    if (token >= N) return;
    const float* xr = x + (size_t)token * D;
    float acc[8];
#pragma unroll
    for (int e = 0; e < 8; ++e) acc[e] = 0.f;
    for (int d0 = 0; d0 < D; d0 += 64) {
        float xv = xr[d0 + lane];
#pragma unroll
        for (int e = 0; e < 8; ++e)
            acc[e] += xv * Wr[e * D + d0 + lane];
    }
#pragma unroll
    for (int e = 0; e < 8; ++e) {
        float v = acc[e];
        for (int off = 32; off > 0; off >>= 1)
            v += __shfl_xor(v, off, 64);
        acc[e] = v;
    }
    if (lane == 0) {
        int best = 0;
        float bv = acc[0] + br[0];
#pragma unroll
        for (int e = 1; e < 8; ++e) {
            float lv = acc[e] + br[e];
            if (lv > bv) { bv = lv; best = e; }
        }
        ids[token] = best;
    }
}

__global__ void hist_kernel(const int* __restrict__ ids,
                            int* __restrict__ blockHist, int N) {
    __shared__ int h[8];
    if (threadIdx.x < 8) h[threadIdx.x] = 0;
    __syncthreads();
    int n = blockIdx.x * 256 + threadIdx.x;
    if (n < N) atomicAdd(&h[ids[n]], 1);
    __syncthreads();
    if (threadIdx.x < 8)
        blockHist[blockIdx.x * 8 + threadIdx.x] = h[threadIdx.x];
}

// ---------------- Single-block scan: block offsets + kcnt ----------------
__global__ void scan_kernel(const int* __restrict__ blockHist,
                            int* __restrict__ blockOff,
                            int* __restrict__ kcnt,
                            const int* __restrict__ capacity,
                            int nb) {
    int e = threadIdx.x;
    if (e < 8) {
        int run = 0;
        for (int b = 0; b < nb; ++b) {
            blockOff[b * 8 + e] = run;
            run += blockHist[b * 8 + e];
        }
        int cap = capacity[0];
        kcnt[e] = run < cap ? run : cap;
    }
}

// ---------------- Rank + compact gather lists + dropped list ---------------
__global__ void rank_kernel(const int* __restrict__ ids,
                            const int* __restrict__ blockOff,
                            const int* __restrict__ capacity,
                            int* __restrict__ gather,
                            int* __restrict__ dropped,   // may be null
                            int* __restrict__ ndropped,  // may be null
                            int N) {
    __shared__ int waveHist[4][8];
    int tid  = threadIdx.x;           // 256 threads = 4 waves
    int n    = blockIdx.x * 256 + tid;
    int lane = tid & 63;
    int wave = tid >> 6;

    int id = (n < N) ? ids[n] : -1;
    int within = 0;
    unsigned long long lt = (1ull << lane) - 1ull;
#pragma unroll
    for (int e = 0; e < 8; ++e) {
        unsigned long long m = __ballot(id == e);
        if (lane == e) waveHist[wave][e] = __popcll(m);
        if (id == e)   within = __popcll(m & lt);
    }
    __syncthreads();
    if (n < N) {
        int prior = blockOff[blockIdx.x * 8 + id];
        for (int w = 0; w < wave; ++w) prior += waveHist[w][id];
        int rank = prior + within + 1;            // 1-based inclusive
        if (rank <= capacity[0]) {
            gather[id * N + (rank - 1)] = n;      // slots 0..kcnt-1 fully written
        } else if (ndropped != nullptr) {
            int di = atomicAdd(ndropped, 1);      // order-free set
            dropped[di] = n;
        }
    }
}

// ---------------- Passthrough for dropped rows only ----------------
__global__ void copy_dropped_kernel(const float* __restrict__ x,
                                    const int* __restrict__ dropped,
                                    const int* __restrict__ ndropped,
                                    float* __restrict__ out, int D) {
    int nd = *ndropped;
    for (int i = blockIdx.x; i < nd; i += gridDim.x) {
        int tok = dropped[i];
        const float4* src = reinterpret_cast<const float4*>(x + (size_t)tok * D);
        float4* dst = reinterpret_cast<float4*>(out + (size_t)tok * D);
        dst[threadIdx.x] = src[threadIdx.x];
    }
}

// ---------------- MFMA expert GEMM, 2-phase pipelined ----------------
// C[tok, f] = Xb[tok,:] . We16[e,f,:] + be[e,f]; A rows gathered per-lane.
#define TM 128
#define TN 128
#define TK 32
__global__ __launch_bounds__(256) void expert_gemm_mfma(
        const __hip_bfloat16* __restrict__ Xb,
        const __hip_bfloat16* __restrict__ We16,
        const float* __restrict__ be,
        const int* __restrict__ kcnt,
        const int* __restrict__ gather,
        float* __restrict__ out,
        int N, int D, int F) {
    int e = blockIdx.z;
    int cnt = kcnt[e];
    int row0 = blockIdx.y * TM;
    if (row0 >= cnt) return;
    int col0 = blockIdx.x * TN;

    __shared__ __hip_bfloat16 As[2][TM * TK];   // 2 x 8 KB
    __shared__ __hip_bfloat16 Bs[2][TM * TK];   // 2 x 8 KB

    int tid  = threadIdx.x;
    int lane = tid & 63;
    int wave = tid >> 6;                        // 4 waves, 2x2 over 64x64
    int wr = wave >> 1, wc = wave & 1;

    // per-thread staging sources: chunk c = i*256+tid -> row r=c>>2, kq=c&3
    const __hip_bfloat16* srcA[2];
    const __hip_bfloat16* srcB[2];
#pragma unroll
    for (int i = 0; i < 2; ++i) {
        int c = i * 256 + tid;
        int r = c >> 2, kq = c & 3;
        int gr = row0 + r;
        int tok = gather[e * N + (gr < cnt ? gr : 0)];   // clamp: cnt>=1 here
        srcA[i] = Xb + (size_t)tok * D + kq * 8;
        srcB[i] = We16 + ((size_t)e * F + col0 + r) * D + kq * 8;
    }

    f32x4_t zero = {0.f, 0.f, 0.f, 0.f};
    f32x4_t acc[4][4];
#pragma unroll
    for (int m = 0; m < 4; ++m)
#pragma unroll
        for (int n = 0; n < 4; ++n) acc[m][n] = zero;

    int kgrp = (lane >> 4) * 8;
    int rA = wr * 64 + (lane & 15);
    int rB = wc * 64 + (lane & 15);

    auto stage = [&](int buf, int k0) {
#pragma unroll
        for (int i = 0; i < 2; ++i) {
            char* la = (char*)(&As[buf][0]) + (size_t)(i * 256 + wave * 64) * 16;
            char* lb = (char*)(&Bs[buf][0]) + (size_t)(i * 256 + wave * 64) * 16;
            async_load16(srcA[i] + k0, la);
            async_load16(srcB[i] + k0, lb);
        }
    };

    stage(0, 0);
    __syncthreads();                 // vmcnt(0) drain + barrier: buf0 ready
    int cur = 0;
    for (int k0 = 0; k0 < D; k0 += TK) {
        if (k0 + TK < D) stage(cur ^ 1, k0 + TK);   // prefetch BEFORE compute

        const short* Ab = reinterpret_cast<const short*>(&As[cur][0]);
        const short* Bb = reinterpret_cast<const short*>(&Bs[cur][0]);
        short8_t a[4], b[4];
#pragma unroll
        for (int m = 0; m < 4; ++m)
            a[m] = *reinterpret_cast<const short8_t*>(&Ab[(rA + m * 16) * TK + kgrp]);
#pragma unroll
        for (int n = 0; n < 4; ++n)
            b[n] = *reinterpret_cast<const short8_t*>(&Bb[(rB + n * 16) * TK + kgrp]);
#pragma unroll
        for (int m = 0; m < 4; ++m)
#pragma unroll
            for (int n = 0; n < 4; ++n)
                acc[m][n] = __builtin_amdgcn_mfma_f32_16x16x32_bf16(
                    a[m], b[n], acc[m][n], 0, 0, 0);

        __syncthreads();             // single drain per K-tile (stage complete,
        cur ^= 1;                    // reads of buf[cur] consumed)
    }

    // epilogue: D-frag row = token-dim (lane>>4)*4+r, col = f-dim lane&15
    int fcol = col0 + wc * 64 + (lane & 15);
    float bias[4];
#pragma unroll
    for (int n = 0; n < 4; ++n) bias[n] = be[e * F + fcol + n * 16];
#pragma unroll
    for (int m = 0; m < 4; ++m) {
        int gr0 = row0 + wr * 64 + m * 16 + (lane >> 4) * 4;
#pragma unroll
        for (int r = 0; r < 4; ++r) {
            int gr = gr0 + r;
            if (gr >= cnt) continue;
            int tok = gather[e * N + gr];
#pragma unroll
            for (int n = 0; n < 4; ++n)
                out[(size_t)tok * F + fcol + n * 16] = acc[m][n][r] + bias[n];
        }
    }
}

// ---------------- fp32 fallback GEMM (round-1, known-good) ----------------
#define BM 64
#define BN 64
#define BK 16
__global__ __launch_bounds__(256) void expert_gemm_f32(
        const float* __restrict__ x,
        const float* __restrict__ We,
        const float* __restrict__ be,
        const int* __restrict__ gather,
        const int* __restrict__ kcnt,
        float* __restrict__ out,
        int N, int D, int F) {
    int e = blockIdx.z;
    int cnt = kcnt[e];
    int row0 = blockIdx.y * BM;
    if (row0 >= cnt) return;
    int col0 = blockIdx.x * BN;

    const float* W = We + (size_t)e * F * D;
    __shared__ float As[BK][BM];
    __shared__ float Bs[BK][BN];

    int tid = threadIdx.x;
    int tx = tid & 15, ty = tid >> 4;
    int rA = tid >> 4, kkA = tid & 15;

    int trow[4];
#pragma unroll
    for (int i = 0; i < 4; ++i) {
        int gr = row0 + rA + i * 16;
        trow[i] = (gr < cnt) ? gather[e * N + gr] : -1;
    }
    float acc[4][4];
#pragma unroll
    for (int i = 0; i < 4; ++i)
#pragma unroll
        for (int j = 0; j < 4; ++j) acc[i][j] = 0.f;

    for (int k0 = 0; k0 < D; k0 += BK) {
#pragma unroll
        for (int i = 0; i < 4; ++i) {
            float v = 0.f;
            if (trow[i] >= 0) v = x[(size_t)trow[i] * D + k0 + kkA];
            As[kkA][rA + i * 16] = v;
        }
#pragma unroll
        for (int i = 0; i < 4; ++i) {
            int f = rA + i * 16;
            Bs[kkA][f] = W[(size_t)(col0 + f) * D + k0 + kkA];
        }
        __syncthreads();
#pragma unroll
        for (int kk = 0; kk < BK; ++kk) {
            float a[4], b[4];
#pragma unroll
            for (int i = 0; i < 4; ++i) a[i] = As[kk][ty * 4 + i];
#pragma unroll
            for (int j = 0; j < 4; ++j) b[j] = Bs[kk][tx * 4 + j];
#pragma unroll
            for (int i = 0; i < 4; ++i)
#pragma unroll
                for (int j = 0; j < 4; ++j)
                    acc[i][j] += a[i] * b[j];
        }
        __syncthreads();
    }
#pragma unroll
    for (int i = 0; i < 4; ++i) {
        int gr = row0 + ty * 4 + i;
        if (gr >= cnt) continue;
        int tokn = gather[e * N + gr];
        float4 v;
        v.x = acc[i][0] + be[e * F + col0 + tx * 4 + 0];
        v.y = acc[i][1] + be[e * F + col0 + tx * 4 + 1];
        v.z = acc[i][2] + be[e * F + col0 + tx * 4 + 2];
        v.w = acc[i][3] + be[e * F + col0 + tx * 4 + 3];
        *reinterpret_cast<float4*>(out + (size_t)tokn * F + col0 + tx * 4) = v;
    }
}

extern "C" void kernel_launch(void* const* d_in, const int* in_sizes, int n_in,
                              void* d_out, int out_size, void* d_ws, size_t ws_size,
                              hipStream_t stream) {
    const float* x        = (const float*)d_in[0];
    const float* Wr       = (const float*)d_in[1];
    const float* br       = (const float*)d_in[2];
    const float* We       = (const float*)d_in[3];
    const float* be       = (const float*)d_in[4];
    const int*   capacity = (const int*)d_in[5];

    int E = in_sizes[2];               // 8
    int D = in_sizes[1] / E;           // 1024
    int N = in_sizes[0] / D;           // 8192
    int F = in_sizes[4] / E;           // 1024
    int nb = (N + 255) / 256;

    float* out = (float*)d_out;

    // ---- workspace layout (meta first so the fallback fits in small ws) ----
    char* w = (char*)d_ws;
    size_t off = 0;
    auto take = [&](size_t bytes) {
        size_t p = off;
        off = (off + bytes + 255) & ~(size_t)255;
        return p;
    };
    int* ids       = (int*)(w + take((size_t)N * 4));
    int* blockHist = (int*)(w + take(((size_t)nb * 8 + 1) * 4));  // + ndropped
    int* ndropped  = blockHist + (size_t)nb * 8;
    int* blockOff  = (int*)(w + take((size_t)nb * 8 * 4));
    int* kcnt      = (int*)(w + take(8 * 4));
    int* gather    = (int*)(w + take((size_t)E * N * 4));
    int* dropped   = (int*)(w + take((size_t)N * 4));
    size_t small_need = off;
    __hip_bfloat16* Xb   = (__hip_bfloat16*)(w + take((size_t)N * D * 2));
    __hip_bfloat16* We16 = (__hip_bfloat16*)(w + take((size_t)E * F * D * 2));
    size_t full_need = off;

    bool fast = (ws_size >= full_need);

    if (fast) {
        // zero hist + ndropped in one shot
        hipMemsetAsync(blockHist, 0, ((size_t)nb * 8 + 1) * 4, stream);
        int nRouterBlocks = (N + 3) / 4;               // 2048
        int nConvBlocks = 512;
        prep_kernel<<<nRouterBlocks + nConvBlocks, 256, 0, stream>>>(
            x, Wr, br, We, ids, blockHist, Xb, We16,
            N, D, nRouterBlocks, (size_t)E * F * D);
        scan_kernel<<<1, 64, 0, stream>>>(blockHist, blockOff, kcnt, capacity, nb);
        rank_kernel<<<nb, 256, 0, stream>>>(ids, blockOff, capacity,
                                            gather, dropped, ndropped, N);
        {
            dim3 g(F / TN, (N + TM - 1) / TM, E);      // early-exit past kcnt
            expert_gemm_mfma<<<g, 256, 0, stream>>>(Xb, We16, be, kcnt, gather,
                                                    out, N, D, F);
        }
        copy_dropped_kernel<<<256, 256, 0, stream>>>(x, dropped, ndropped, out, D);
    } else if (small_need <= ws_size) {
        // fallback: full passthrough + fp32 GEMM (round-1 behavior)
        hipMemcpyAsync(out, x, (size_t)N * D * sizeof(float),
                       hipMemcpyDeviceToDevice, stream);
        router_kernel<<<(N + 3) / 4, 256, 0, stream>>>(x, Wr, br, ids, N, D);
        hist_kernel<<<nb, 256, 0, stream>>>(ids, blockHist, N);
        scan_kernel<<<1, 64, 0, stream>>>(blockHist, blockOff, kcnt, capacity, nb);
        rank_kernel<<<nb, 256, 0, stream>>>(ids, blockOff, capacity,
                                            gather, nullptr, nullptr, N);
        dim3 g(F / BN, (N + BM - 1) / BM, E);
        expert_gemm_f32<<<g, 256, 0, stream>>>(x, We, be, gather, kcnt,
                                               out, N, D, F);
    }
}

// Round 4
// 95.029 us; speedup vs baseline: 1.0031x; 1.0031x over previous
//
#include <hip/hip_runtime.h>
#include <hip/hip_bf16.h>

// ---------------------------------------------------------------------------
// MoE: router (argmax over 8 experts) + capacity drop + per-expert linear.
// Round 4:
//  - prep: 512 blocks; each wave routes 4 tokens (16 independent x-streams,
//    acc in regs) + writes bf16 Xb; every block also converts an interleaved
//    We->bf16 slice (no dedicated tail blocks).
//  - expert GEMM: 128x128 BK=32 mfma_f32_16x16x32_bf16, TRIPLE-buffered LDS
//    with counted vmcnt(4) (T4: loads stay in flight across barriers),
//    [kq][row][16B] LDS layout (2-way bank = free), XCD swizzle: expert e
//    pinned to XCD e (A+B panels = 4 MB = one XCD L2).
//  - dropped rows copied directly; kept rows written by GEMM scatter.
// ---------------------------------------------------------------------------

typedef short short8_t __attribute__((ext_vector_type(8)));
typedef float f32x4_t  __attribute__((ext_vector_type(4)));

typedef const unsigned int __attribute__((address_space(1))) gu32;
typedef unsigned int       __attribute__((address_space(3))) lu32;

__device__ __forceinline__ void async_load16(const void* gptr, void* lptr) {
    __builtin_amdgcn_global_load_lds((gu32*)gptr, (lu32*)lptr, 16, 0, 0);
}

// ---------------- fused prep: router(4 tok/wave) + Xb + hist + We conv -----
__global__ __launch_bounds__(256) void prep_kernel(
        const float* __restrict__ x,
        const float* __restrict__ Wr,
        const float* __restrict__ br,
        const float* __restrict__ We,
        int* __restrict__ ids,
        int* __restrict__ blockHist,
        __hip_bfloat16* __restrict__ Xb,
        __hip_bfloat16* __restrict__ We16,
        int N, int D, size_t weN) {
    int tid  = threadIdx.x;
    int lane = tid & 63;
    int wave = tid >> 6;
    int tbase = blockIdx.x * 16 + wave * 4;   // 4 tokens per wave

    const float4* xp[4];
#pragma unroll
    for (int t = 0; t < 4; ++t) {
        int tk = tbase + t; if (tk >= N) tk = N - 1;
        xp[t] = reinterpret_cast<const float4*>(x + (size_t)tk * D);
    }

    float acc[4][8];
#pragma unroll
    for (int t = 0; t < 4; ++t)
#pragma unroll
        for (int e = 0; e < 8; ++e) acc[t][e] = 0.f;

#pragma unroll
    for (int p = 0; p < 4; ++p) {             // 4*64 float4 = 1024 floats
        float4 xv[4];
#pragma unroll
        for (int t = 0; t < 4; ++t) xv[t] = xp[t][p * 64 + lane];
        // bf16 copy of x (token order)
#pragma unroll
        for (int t = 0; t < 4; ++t) {
            if (tbase + t < N) {
                union { __hip_bfloat16 h[4]; uint2 u; } c;
                c.h[0] = __float2bfloat16(xv[t].x);
                c.h[1] = __float2bfloat16(xv[t].y);
                c.h[2] = __float2bfloat16(xv[t].z);
                c.h[3] = __float2bfloat16(xv[t].w);
                *reinterpret_cast<uint2*>(
                    Xb + (size_t)(tbase + t) * D + (p * 64 + lane) * 4) = c.u;
            }
        }
#pragma unroll
        for (int e = 0; e < 8; ++e) {
            float4 w = reinterpret_cast<const float4*>(Wr + e * D)[p * 64 + lane];
#pragma unroll
            for (int t = 0; t < 4; ++t)
                acc[t][e] += xv[t].x * w.x + xv[t].y * w.y
                           + xv[t].z * w.z + xv[t].w * w.w;
        }
    }
    // wave reduce all 32 accumulators
#pragma unroll
    for (int t = 0; t < 4; ++t)
#pragma unroll
        for (int e = 0; e < 8; ++e) {
            float s = acc[t][e];
            for (int off = 32; off > 0; off >>= 1)
                s += __shfl_xor(s, off, 64);
            acc[t][e] = s;
        }
    if (lane == 0) {
#pragma unroll
        for (int t = 0; t < 4; ++t) {
            if (tbase + t >= N) break;
            int best = 0;
            float bv = acc[t][0] + br[0];
#pragma unroll
            for (int e = 1; e < 8; ++e) {
                float lv = acc[t][e] + br[e];
                if (lv > bv) { bv = lv; best = e; }  // strict >: first-max argmax
            }
            ids[tbase + t] = best;
            atomicAdd(&blockHist[((tbase + t) >> 8) * 8 + best], 1);
        }
    }

    // ---- interleaved We fp32 -> bf16 slice ----
    size_t i = ((size_t)blockIdx.x * 256 + tid) * 8;
    size_t stride = (size_t)gridDim.x * 256 * 8;
    for (; i < weN; i += stride) {
        float4 v0 = *reinterpret_cast<const float4*>(We + i);
        float4 v1 = *reinterpret_cast<const float4*>(We + i + 4);
        union { __hip_bfloat16 h[8]; uint4 u; } t;
        t.h[0] = __float2bfloat16(v0.x); t.h[1] = __float2bfloat16(v0.y);
        t.h[2] = __float2bfloat16(v0.z); t.h[3] = __float2bfloat16(v0.w);
        t.h[4] = __float2bfloat16(v1.x); t.h[5] = __float2bfloat16(v1.y);
        t.h[6] = __float2bfloat16(v1.z); t.h[7] = __float2bfloat16(v1.w);
        *reinterpret_cast<uint4*>(We16 + i) = t.u;
    }
}

// ---------------- Single-block scan: block offsets + kcnt ----------------
__global__ void scan_kernel(const int* __restrict__ blockHist,
                            int* __restrict__ blockOff,
                            int* __restrict__ kcnt,
                            const int* __restrict__ capacity,
                            int nb) {
    int e = threadIdx.x;
    if (e < 8) {
        int run = 0;
        for (int b = 0; b < nb; ++b) {
            blockOff[b * 8 + e] = run;
            run += blockHist[b * 8 + e];
        }
        int cap = capacity[0];
        kcnt[e] = run < cap ? run : cap;
    }
}

// ---------------- Rank + compact gather lists + dropped list ---------------
__global__ void rank_kernel(const int* __restrict__ ids,
                            const int* __restrict__ blockOff,
                            const int* __restrict__ capacity,
                            int* __restrict__ gather,
                            int* __restrict__ dropped,   // may be null
                            int* __restrict__ ndropped,  // may be null
                            int N) {
    __shared__ int waveHist[4][8];
    int tid  = threadIdx.x;           // 256 threads = 4 waves
    int n    = blockIdx.x * 256 + tid;
    int lane = tid & 63;
    int wave = tid >> 6;

    int id = (n < N) ? ids[n] : -1;
    int within = 0;
    unsigned long long lt = (1ull << lane) - 1ull;
#pragma unroll
    for (int e = 0; e < 8; ++e) {
        unsigned long long m = __ballot(id == e);
        if (lane == e) waveHist[wave][e] = __popcll(m);
        if (id == e)   within = __popcll(m & lt);
    }
    __syncthreads();
    if (n < N) {
        int prior = blockOff[blockIdx.x * 8 + id];
        for (int w = 0; w < wave; ++w) prior += waveHist[w][id];
        int rank = prior + within + 1;            // 1-based inclusive
        if (rank <= capacity[0]) {
            gather[id * N + (rank - 1)] = n;      // slots 0..kcnt-1 fully written
        } else if (ndropped != nullptr) {
            int di = atomicAdd(ndropped, 1);      // order-free set
            dropped[di] = n;
        }
    }
}

// ---------------- Passthrough for dropped rows only ----------------
__global__ void copy_dropped_kernel(const float* __restrict__ x,
                                    const int* __restrict__ dropped,
                                    const int* __restrict__ ndropped,
                                    float* __restrict__ out, int D) {
    int nd = *ndropped;
    for (int i = blockIdx.x; i < nd; i += gridDim.x) {
        int tok = dropped[i];
        const float4* src = reinterpret_cast<const float4*>(x + (size_t)tok * D);
        float4* dst = reinterpret_cast<float4*>(out + (size_t)tok * D);
        dst[threadIdx.x] = src[threadIdx.x];
    }
}

// ---------------- MFMA expert GEMM: triple-buffer, counted vmcnt -----------
// C[tok, f] = Xb[tok,:] . We16[e,f,:] + be[e,f]; A rows gathered per-lane.
// LDS layout per buffer: [A|B][kq 0..3][row 0..127][8 bf16] (16B chunks).
#define TM 128
#define TN 128
#define TK 32
__global__ __launch_bounds__(256) void expert_gemm_mfma(
        const __hip_bfloat16* __restrict__ Xb,
        const __hip_bfloat16* __restrict__ We16,
        const float* __restrict__ be,
        const int* __restrict__ kcnt,
        const int* __restrict__ gather,
        float* __restrict__ out,
        int N, int D, int F) {
    // XCD swizzle: XCD (b%8) owns expert (b%8); A+B panels fit its L2.
    int b = blockIdx.x;
    int nper = gridDim.x >> 3;            // blocks per expert
    int sw = (b & 7) * nper + (b >> 3);
    int e = sw / nper;
    int rem = sw - e * nper;
    int colTiles = F / TN;
    int xt = rem % colTiles;
    int yt = rem / colTiles;

    int cnt = kcnt[e];
    int row0 = yt * TM;
    if (row0 >= cnt) return;
    int col0 = xt * TN;

    __shared__ __hip_bfloat16 lds[3][2][4][TM][8];   // 3 bufs x (A 8KB + B 8KB)

    int tid  = threadIdx.x;
    int lane = tid & 63;
    int wave = tid >> 6;                  // 4 waves, 2x2 over 64x64
    int wr = wave >> 1, wc = wave & 1;

    // staging sources: chunk c = i*256+tid -> kq=c>>7, row=c&127
    const __hip_bfloat16* srcA[2];
    const __hip_bfloat16* srcB[2];
#pragma unroll
    for (int i = 0; i < 2; ++i) {
        int c = i * 256 + tid;
        int r = c & 127, kq = c >> 7;
        int gr = row0 + r;
        int tok = gather[e * N + (gr < cnt ? gr : cnt - 1)];
        srcA[i] = Xb + (size_t)tok * D + kq * 8;
        srcB[i] = We16 + ((size_t)e * F + col0 + r) * D + kq * 8;
    }

    f32x4_t zero = {0.f, 0.f, 0.f, 0.f};
    f32x4_t acc[4][4];
#pragma unroll
    for (int m = 0; m < 4; ++m)
#pragma unroll
        for (int n = 0; n < 4; ++n) acc[m][n] = zero;

    int kgrpq = lane >> 4;                // which k-quarter this lane reads
    int rA = wr * 64 + (lane & 15);
    int rB = wc * 64 + (lane & 15);

    auto stage = [&](int buf, int k0) {
#pragma unroll
        for (int i = 0; i < 2; ++i) {
            char* la = (char*)(&lds[buf][0][0][0][0]) + (size_t)(i * 256 + wave * 64) * 16;
            char* lb = (char*)(&lds[buf][1][0][0][0]) + (size_t)(i * 256 + wave * 64) * 16;
            async_load16(srcA[i] + k0, la);
            async_load16(srcB[i] + k0, lb);
        }
    };

    const int nt = D / TK;                // 32
    stage(0, 0);
    if (nt > 1) stage(1, TK);

    for (int t = 0; t < nt; ++t) {
        // T4: keep the newest stage's 4 loads in flight; drain only at the end.
        if (t + 1 < nt) {
            asm volatile("s_waitcnt vmcnt(4)\n\ts_barrier" ::: "memory");
        } else {
            asm volatile("s_waitcnt vmcnt(0)\n\ts_barrier" ::: "memory");
        }
        if (t + 2 < nt) stage((t + 2) % 3, (t + 2) * TK);

        int cb = t % 3;
        const short* Ab = reinterpret_cast<const short*>(&lds[cb][0][0][0][0]);
        const short* Bb = reinterpret_cast<const short*>(&lds[cb][1][0][0][0]);
        short8_t a[4], bfr[4];
#pragma unroll
        for (int m = 0; m < 4; ++m)
            a[m] = *reinterpret_cast<const short8_t*>(
                &Ab[(kgrpq * 128 + rA + m * 16) * 8]);
#pragma unroll
        for (int n = 0; n < 4; ++n)
            bfr[n] = *reinterpret_cast<const short8_t*>(
                &Bb[(kgrpq * 128 + rB + n * 16) * 8]);
#pragma unroll
        for (int m = 0; m < 4; ++m)
#pragma unroll
            for (int n = 0; n < 4; ++n)
                acc[m][n] = __builtin_amdgcn_mfma_f32_16x16x32_bf16(
                    a[m], bfr[n], acc[m][n], 0, 0, 0);
    }

    // epilogue: D-frag row = token-dim (lane>>4)*4+r, col = f-dim lane&15
    int fcol = col0 + wc * 64 + (lane & 15);
    float bias[4];
#pragma unroll
    for (int n = 0; n < 4; ++n) bias[n] = be[e * F + fcol + n * 16];
#pragma unroll
    for (int m = 0; m < 4; ++m) {
        int gr0 = row0 + wr * 64 + m * 16 + (lane >> 4) * 4;
#pragma unroll
        for (int r = 0; r < 4; ++r) {
            int gr = gr0 + r;
            if (gr >= cnt) continue;
            int tok = gather[e * N + gr];
#pragma unroll
            for (int n = 0; n < 4; ++n)
                out[(size_t)tok * F + fcol + n * 16] = acc[m][n][r] + bias[n];
        }
    }
}

// ---------------- fp32 fallback path (small ws), round-1 known-good --------
__global__ void router_kernel(const float* __restrict__ x,
                              const float* __restrict__ Wr,
                              const float* __restrict__ br,
                              int* __restrict__ ids,
                              int N, int D) {
    int gtid = blockIdx.x * blockDim.x + threadIdx.x;
    int token = gtid >> 6;
    int lane  = threadIdx.x & 63;
    if (token >= N) return;
    const float* xr = x + (size_t)token * D;
    float acc[8];
#pragma unroll
    for (int e = 0; e < 8; ++e) acc[e] = 0.f;
    for (int d0 = 0; d0 < D; d0 += 64) {
        float xv = xr[d0 + lane];
#pragma unroll
        for (int e = 0; e < 8; ++e)
            acc[e] += xv * Wr[e * D + d0 + lane];
    }
#pragma unroll
    for (int e = 0; e < 8; ++e) {
        float v = acc[e];
        for (int off = 32; off > 0; off >>= 1)
            v += __shfl_xor(v, off, 64);
        acc[e] = v;
    }
    if (lane == 0) {
        int best = 0;
        float bv = acc[0] + br[0];
#pragma unroll
        for (int e = 1; e < 8; ++e) {
            float lv = acc[e] + br[e];
            if (lv > bv) { bv = lv; best = e; }
        }
        ids[token] = best;
    }
}

__global__ void hist_kernel(const int* __restrict__ ids,
                            int* __restrict__ blockHist, int N) {
    __shared__ int h[8];
    if (threadIdx.x < 8) h[threadIdx.x] = 0;
    __syncthreads();
    int n = blockIdx.x * 256 + threadIdx.x;
    if (n < N) atomicAdd(&h[ids[n]], 1);
    __syncthreads();
    if (threadIdx.x < 8)
        blockHist[blockIdx.x * 8 + threadIdx.x] = h[threadIdx.x];
}

#define BM 64
#define BN 64
#define BK 16
__global__ __launch_bounds__(256) void expert_gemm_f32(
        const float* __restrict__ x,
        const float* __restrict__ We,
        const float* __restrict__ be,
        const int* __restrict__ gather,
        const int* __restrict__ kcnt,
        float* __restrict__ out,
        int N, int D, int F) {
    int e = blockIdx.z;
    int cnt = kcnt[e];
    int row0 = blockIdx.y * BM;
    if (row0 >= cnt) return;
    int col0 = blockIdx.x * BN;

    const float* W = We + (size_t)e * F * D;
    __shared__ float As[BK][BM];
    __shared__ float Bs[BK][BN];

    int tid = threadIdx.x;
    int tx = tid & 15, ty = tid >> 4;
    int rA = tid >> 4, kkA = tid & 15;

    int trow[4];
#pragma unroll
    for (int i = 0; i < 4; ++i) {
        int gr = row0 + rA + i * 16;
        trow[i] = (gr < cnt) ? gather[e * N + gr] : -1;
    }
    float acc[4][4];
#pragma unroll
    for (int i = 0; i < 4; ++i)
#pragma unroll
        for (int j = 0; j < 4; ++j) acc[i][j] = 0.f;

    for (int k0 = 0; k0 < D; k0 += BK) {
#pragma unroll
        for (int i = 0; i < 4; ++i) {
            float v = 0.f;
            if (trow[i] >= 0) v = x[(size_t)trow[i] * D + k0 + kkA];
            As[kkA][rA + i * 16] = v;
        }
#pragma unroll
        for (int i = 0; i < 4; ++i) {
            int f = rA + i * 16;
            Bs[kkA][f] = W[(size_t)(col0 + f) * D + k0 + kkA];
        }
        __syncthreads();
#pragma unroll
        for (int kk = 0; kk < BK; ++kk) {
            float a[4], b[4];
#pragma unroll
            for (int i = 0; i < 4; ++i) a[i] = As[kk][ty * 4 + i];
#pragma unroll
            for (int j = 0; j < 4; ++j) b[j] = Bs[kk][tx * 4 + j];
#pragma unroll
            for (int i = 0; i < 4; ++i)
#pragma unroll
                for (int j = 0; j < 4; ++j)
                    acc[i][j] += a[i] * b[j];
        }
        __syncthreads();
    }
#pragma unroll
    for (int i = 0; i < 4; ++i) {
        int gr = row0 + ty * 4 + i;
        if (gr >= cnt) continue;
        int tokn = gather[e * N + gr];
        float4 v;
        v.x = acc[i][0] + be[e * F + col0 + tx * 4 + 0];
        v.y = acc[i][1] + be[e * F + col0 + tx * 4 + 1];
        v.z = acc[i][2] + be[e * F + col0 + tx * 4 + 2];
        v.w = acc[i][3] + be[e * F + col0 + tx * 4 + 3];
        *reinterpret_cast<float4*>(out + (size_t)tokn * F + col0 + tx * 4) = v;
    }
}

extern "C" void kernel_launch(void* const* d_in, const int* in_sizes, int n_in,
                              void* d_out, int out_size, void* d_ws, size_t ws_size,
                              hipStream_t stream) {
    const float* x        = (const float*)d_in[0];
    const float* Wr       = (const float*)d_in[1];
    const float* br       = (const float*)d_in[2];
    const float* We       = (const float*)d_in[3];
    const float* be       = (const float*)d_in[4];
    const int*   capacity = (const int*)d_in[5];

    int E = in_sizes[2];               // 8
    int D = in_sizes[1] / E;           // 1024
    int N = in_sizes[0] / D;           // 8192
    int F = in_sizes[4] / E;           // 1024
    int nb = (N + 255) / 256;

    float* out = (float*)d_out;

    // ---- workspace layout (meta first so the fallback fits in small ws) ----
    char* w = (char*)d_ws;
    size_t off = 0;
    auto take = [&](size_t bytes) {
        size_t p = off;
        off = (off + bytes + 255) & ~(size_t)255;
        return p;
    };
    int* ids       = (int*)(w + take((size_t)N * 4));
    int* blockHist = (int*)(w + take(((size_t)nb * 8 + 1) * 4));  // + ndropped
    int* ndropped  = blockHist + (size_t)nb * 8;
    int* blockOff  = (int*)(w + take((size_t)nb * 8 * 4));
    int* kcnt      = (int*)(w + take(8 * 4));
    int* gather    = (int*)(w + take((size_t)E * N * 4));
    int* dropped   = (int*)(w + take((size_t)N * 4));
    size_t small_need = off;
    __hip_bfloat16* Xb   = (__hip_bfloat16*)(w + take((size_t)N * D * 2));
    __hip_bfloat16* We16 = (__hip_bfloat16*)(w + take((size_t)E * F * D * 2));
    size_t full_need = off;

    bool fast = (ws_size >= full_need);

    if (fast) {
        hipMemsetAsync(blockHist, 0, ((size_t)nb * 8 + 1) * 4, stream);
        prep_kernel<<<(N + 15) / 16, 256, 0, stream>>>(
            x, Wr, br, We, ids, blockHist, Xb, We16, N, D, (size_t)E * F * D);
        scan_kernel<<<1, 64, 0, stream>>>(blockHist, blockOff, kcnt, capacity, nb);
        rank_kernel<<<nb, 256, 0, stream>>>(ids, blockOff, capacity,
                                            gather, dropped, ndropped, N);
        {
            int rowTiles = (N + TM - 1) / TM;      // 64
            int colTiles = F / TN;                 // 8
            int nwg = E * rowTiles * colTiles;     // 4096, %8==0 (bijective swz)
            expert_gemm_mfma<<<nwg, 256, 0, stream>>>(Xb, We16, be, kcnt, gather,
                                                      out, N, D, F);
        }
        copy_dropped_kernel<<<256, 256, 0, stream>>>(x, dropped, ndropped, out, D);
    } else if (small_need <= ws_size) {
        // fallback: full passthrough + fp32 GEMM (round-1 behavior)
        hipMemcpyAsync(out, x, (size_t)N * D * sizeof(float),
                       hipMemcpyDeviceToDevice, stream);
        router_kernel<<<(N + 3) / 4, 256, 0, stream>>>(x, Wr, br, ids, N, D);
        hist_kernel<<<nb, 256, 0, stream>>>(ids, blockHist, N);
        scan_kernel<<<1, 64, 0, stream>>>(blockHist, blockOff, kcnt, capacity, nb);
        rank_kernel<<<nb, 256, 0, stream>>>(ids, blockOff, capacity,
                                            gather, nullptr, nullptr, N);
        dim3 g(F / BN, (N + BM - 1) / BM, E);
        expert_gemm_f32<<<g, 256, 0, stream>>>(x, We, be, gather, kcnt,
                                               out, N, D, F);
    }
}